// Round 6
// baseline (424.566 us; speedup 1.0000x reference)
//
#include <hip/hip_runtime.h>
#include <hip/hip_bf16.h>
#include <math.h>

#define NPTS 2000000
#define NCL 64
#define EPSF 1e-8f
#define NB_SUMS 2048
#define NB_INTRA 2048
#define NREP 64  // global partial replicas for pass-1 flush

// ws float layout:
//   part[NREP][1088]   @ 0        (sums[c][d] at c*16+d, counts at 1024+c)
//   ticket1, ticket2   @ 69632    (ints)
//   means[1024]        @ 69636
//   icnt[64]           @ 70660
//   scal[2]            @ 70724    (inter_loss, reg_loss)
//   pintra[NB_INTRA]   @ 70726
#define WS_PART   0
#define WS_TKT1   69632
#define WS_TKT2   69633
#define WS_MEANS  69636
#define WS_ICNT   70660
#define WS_SCAL   70724
#define WS_PINTRA 70726
#define WS_ZERO_FLOATS 69634  // part + tickets must be zeroed each call

typedef __attribute__((ext_vector_type(8))) short bf16x8;
typedef __attribute__((ext_vector_type(4))) float f32x4;

__device__ __forceinline__ unsigned pk2(float a, float b) {
    __hip_bfloat162 h = __float22bfloat162_rn(make_float2(a, b));
    union { __hip_bfloat162 h; unsigned u; } x;
    x.h = h;
    return x.u;  // low 16 = a, high 16 = b
}
__device__ __forceinline__ unsigned oh2(int a, int b, int c) {
    return (a == c ? 0x3F80u : 0u) | (b == c ? 0x3F800000u : 0u);  // bf16 {1.0,1.0}
}

// Pass 1: segment-sum via one-hot MFMA (verified R3). Flush to NREP global
// replicas; LAST block (ticket) reduces them and computes means/icnt/inter/reg.
__global__ void __launch_bounds__(256) k_sums(const float4* __restrict__ feat,
                                              const int* __restrict__ lab,
                                              float* __restrict__ ws) {
    __shared__ __align__(16) float smem[4 * 1088];
    __shared__ int s_last;
    const int tid = threadIdx.x;
    const int l = tid & 63, w = tid >> 6, g = l >> 4, mcol = l & 15;

    const unsigned lds0 = (unsigned)(uintptr_t)(&smem[0]);
    const unsigned trb = lds0 + (unsigned)(w * 2048 + l * 8);
    uint2* tw = (uint2*)((unsigned short*)smem + w * 1024);

    f32x4 accS[4], accC[4];
#pragma unroll
    for (int i = 0; i < 4; ++i) {
        accS[i] = (f32x4){0.f, 0.f, 0.f, 0.f};
        accC[i] = (f32x4){0.f, 0.f, 0.f, 0.f};
    }
    bf16x8 ones;
#pragma unroll
    for (int i = 0; i < 8; ++i) ones[i] = (short)0x3F80;

    const int wstride = gridDim.x * 4;
    for (int wc = blockIdx.x * 4 + w; wc * 64 < NPTS; wc += wstride) {
        const int P = wc * 64;
        float4 f0 = feat[P * 4 + l];
        float4 f1 = feat[P * 4 + 64 + l];
        float4 f2 = feat[P * 4 + 128 + l];
        float4 f3 = feat[P * 4 + 192 + l];
        int4 La0 = *(const int4*)(lab + P + 4 * g);
        int4 Lb0 = *(const int4*)(lab + P + 16 + 4 * g);
        int4 La1 = *(const int4*)(lab + P + 32 + 4 * g);
        int4 Lb1 = *(const int4*)(lab + P + 48 + 4 * g);

        tw[l]       = make_uint2(pk2(f0.x, f0.y), pk2(f0.z, f0.w));
        tw[64 + l]  = make_uint2(pk2(f1.x, f1.y), pk2(f1.z, f1.w));
        tw[128 + l] = make_uint2(pk2(f2.x, f2.y), pk2(f2.z, f2.w));
        tw[192 + l] = make_uint2(pk2(f3.x, f3.y), pk2(f3.z, f3.w));

        asm volatile("s_waitcnt lgkmcnt(0)" ::: "memory");
        unsigned long long t00, t01, t10, t11;
        asm volatile("ds_read_b64_tr_b16 %0, %1 offset:0"    : "=v"(t00) : "v"(trb));
        asm volatile("ds_read_b64_tr_b16 %0, %1 offset:512"  : "=v"(t01) : "v"(trb));
        asm volatile("ds_read_b64_tr_b16 %0, %1 offset:1024" : "=v"(t10) : "v"(trb));
        asm volatile("ds_read_b64_tr_b16 %0, %1 offset:1536" : "=v"(t11) : "v"(trb));
        asm volatile("s_waitcnt lgkmcnt(0)" ::: "memory");
        __builtin_amdgcn_sched_barrier(0);

        union { unsigned u[4]; bf16x8 h; } B0, B1;
        B0.u[0] = (unsigned)t00; B0.u[1] = (unsigned)(t00 >> 32);
        B0.u[2] = (unsigned)t01; B0.u[3] = (unsigned)(t01 >> 32);
        B1.u[0] = (unsigned)t10; B1.u[1] = (unsigned)(t10 >> 32);
        B1.u[2] = (unsigned)t11; B1.u[3] = (unsigned)(t11 >> 32);

#pragma unroll
        for (int gp = 0; gp < 4; ++gp) {
            const int c = mcol + (gp << 4);
            union { unsigned u[4]; bf16x8 h; } A0, A1;
            A0.u[0] = oh2(La0.x, La0.y, c); A0.u[1] = oh2(La0.z, La0.w, c);
            A0.u[2] = oh2(Lb0.x, Lb0.y, c); A0.u[3] = oh2(Lb0.z, Lb0.w, c);
            A1.u[0] = oh2(La1.x, La1.y, c); A1.u[1] = oh2(La1.z, La1.w, c);
            A1.u[2] = oh2(Lb1.x, Lb1.y, c); A1.u[3] = oh2(Lb1.z, Lb1.w, c);
            accS[gp] = __builtin_amdgcn_mfma_f32_16x16x32_bf16(A0.h, B0.h, accS[gp], 0, 0, 0);
            accC[gp] = __builtin_amdgcn_mfma_f32_16x16x32_bf16(A0.h, ones, accC[gp], 0, 0, 0);
            accS[gp] = __builtin_amdgcn_mfma_f32_16x16x32_bf16(A1.h, B1.h, accS[gp], 0, 0, 0);
            accC[gp] = __builtin_amdgcn_mfma_f32_16x16x32_bf16(A1.h, ones, accC[gp], 0, 0, 0);
        }
    }

    // per-wave flush to LDS; D layout col=lane&15, row=(lane>>4)*4+reg
    __syncthreads();
    float* fl = smem + w * 1088;
#pragma unroll
    for (int gp = 0; gp < 4; ++gp) {
#pragma unroll
        for (int r = 0; r < 4; ++r) {
            int c = (gp << 4) + ((l >> 4) << 2) + r;
            fl[c * 16 + mcol] = accS[gp][r];
            if (mcol == 0) fl[1024 + c] = accC[gp][r];
        }
    }
    __syncthreads();
    float* dst = ws + WS_PART + (unsigned)(blockIdx.x & (NREP - 1)) * 1088;
    for (int i = tid; i < 1088; i += 256) {
        float s = smem[i] + smem[1088 + i] + smem[2176 + i] + smem[3264 + i];
        unsafeAtomicAdd(&dst[i], s);
    }
    __threadfence();
    __syncthreads();
    if (tid == 0)
        s_last = (atomicAdd((int*)(ws + WS_TKT1), 1) == (int)gridDim.x - 1) ? 1 : 0;
    __syncthreads();
    if (!s_last) return;

    // ---- last block: reduce NREP replicas -> means/icnt/inter/reg ----
    __threadfence();  // acquire: invalidate L1, see all replicas
    const int pg = tid >> 6, jl = tid & 63;
    for (int j = jl; j < 1088; j += 64) {
        float s = 0.f;
#pragma unroll
        for (int pp = 0; pp < 16; ++pp)
            s += ws[WS_PART + (pg * 16 + pp) * 1088 + j];
        smem[pg * 1088 + j] = s;
    }
    __syncthreads();
    for (int j = tid; j < 1088; j += 256)
        smem[j] = smem[j] + smem[1088 + j] + smem[2176 + j] + smem[3264 + j];
    __syncthreads();
    // means into global + padded LDS copy at smem[1088..2175]
    for (int i = tid; i < 1024; i += 256) {
        float m = smem[i] / smem[1024 + (i >> 4)];
        ws[WS_MEANS + i] = m;
        smem[1088 + (i >> 4) * 17 + (i & 15)] = m;
    }
    if (tid < NCL) ws[WS_ICNT + tid] = 1.0f / smem[1024 + tid];
    __syncthreads();

    const float* s_means = smem + 1088;
    float inter = 0.f;
    for (int pr = tid; pr < NCL * NCL; pr += 256) {
        int i = pr >> 6, j = pr & 63;
        if (i != j) {
            float ss = 0.f;
#pragma unroll
            for (int k = 0; k < 16; ++k) {
                float dv = s_means[i * 17 + k] - s_means[j * 17 + k] + EPSF;
                ss += dv * dv;
            }
            float h = fmaxf(3.0f - sqrtf(ss), 0.f);  // 2*INTER_MARGIN
            inter += h * h;
        }
    }
    float reg = 0.f;
    if (tid < NCL) {
        float ss = 0.f;
#pragma unroll
        for (int k = 0; k < 16; ++k) {
            float m = s_means[tid * 17 + k] + EPSF;
            ss += m * m;
        }
        reg = sqrtf(ss);
    }
#pragma unroll
    for (int m = 1; m < 64; m <<= 1) {
        inter += __shfl_xor(inter, m);
        reg += __shfl_xor(reg, m);
    }
    __shared__ float red8[8];
    if ((tid & 63) == 0) { red8[tid >> 6] = inter; red8[4 + (tid >> 6)] = reg; }
    __syncthreads();
    if (tid == 0) {
        ws[WS_SCAL + 0] = (red8[0] + red8[1] + red8[2] + red8[3]) / (float)(NCL * (NCL - 1));
        ws[WS_SCAL + 1] = (red8[4] + red8[5] + red8[6] + red8[7]) / (float)NCL;
    }
}

// Pass 2: acc += h^2 * inv_cnt[label] in registers; last block writes out[0].
__global__ void __launch_bounds__(256) k_intra(const float4* __restrict__ feat,
                                               const int* __restrict__ lab,
                                               float* __restrict__ ws,
                                               float* __restrict__ out) {
    __shared__ float s_m[NCL * 17];
    __shared__ float r4[4];
    __shared__ int s_last;
    const int tid = threadIdx.x;
    for (int i = tid; i < NCL * 16; i += 256)
        s_m[(i >> 4) * 17 + (i & 15)] = ws[WS_MEANS + i];
    for (int i = tid; i < NCL; i += 256) s_m[i * 17 + 16] = ws[WS_ICNT + i];
    __syncthreads();

    float acc = 0.f;
    const int total = NPTS * 4;
    const int stride = gridDim.x * 256;
    for (int idx = blockIdx.x * 256 + tid; idx < total; idx += stride) {
        int p = idx >> 2, q = idx & 3;
        int lb = lab[p];
        float4 v = feat[idx];
        const float* m = &s_m[lb * 17 + q * 4];
        float d0 = v.x - m[0] + EPSF;
        float d1 = v.y - m[1] + EPSF;
        float d2 = v.z - m[2] + EPSF;
        float d3 = v.w - m[3] + EPSF;
        float ss = d0 * d0 + d1 * d1 + d2 * d2 + d3 * d3;
        ss += __shfl_xor(ss, 1);
        ss += __shfl_xor(ss, 2);
        if (q == 0) {
            float h = fmaxf(sqrtf(ss) - 0.5f, 0.f);
            acc += h * h * s_m[lb * 17 + 16];
        }
    }
#pragma unroll
    for (int mm = 1; mm < 64; mm <<= 1) acc += __shfl_xor(acc, mm);
    if ((tid & 63) == 0) r4[tid >> 6] = acc;
    __syncthreads();
    if (tid == 0) ws[WS_PINTRA + blockIdx.x] = r4[0] + r4[1] + r4[2] + r4[3];
    __threadfence();
    __syncthreads();
    if (tid == 0)
        s_last = (atomicAdd((int*)(ws + WS_TKT2), 1) == (int)gridDim.x - 1) ? 1 : 0;
    __syncthreads();
    if (!s_last) return;

    __threadfence();  // acquire
    float v = 0.f;
#pragma unroll
    for (int i = 0; i < NB_INTRA / 256; ++i) v += ws[WS_PINTRA + tid + i * 256];
#pragma unroll
    for (int mm = 1; mm < 64; mm <<= 1) v += __shfl_xor(v, mm);
    if ((tid & 63) == 0) r4[tid >> 6] = v;
    __syncthreads();
    if (tid == 0)
        out[0] = (r4[0] + r4[1] + r4[2] + r4[3]) / (float)NCL +
                 ws[WS_SCAL + 0] + 0.001f * ws[WS_SCAL + 1];
}

extern "C" void kernel_launch(void* const* d_in, const int* in_sizes, int n_in,
                              void* d_out, int out_size, void* d_ws, size_t ws_size,
                              hipStream_t stream) {
    const float4* feat = (const float4*)d_in[0];
    const int* lab = (const int*)d_in[1];
    float* ws = (float*)d_ws;
    float* out = (float*)d_out;

    hipMemsetAsync(d_ws, 0, WS_ZERO_FLOATS * sizeof(float), stream);
    k_sums<<<NB_SUMS, 256, 0, stream>>>(feat, lab, ws);
    k_intra<<<NB_INTRA, 256, 0, stream>>>(feat, lab, ws, out);
}

// Round 7
// 82.202 us; speedup vs baseline: 5.1649x; 5.1649x over previous
//
#include <hip/hip_runtime.h>
#include <hip/hip_bf16.h>
#include <math.h>

#define NPTS 2000000
#define NCL 64
#define EPSF 1e-8f
#define NB_SUMS 1024
#define NPART 1024
#define NB_INTRA 2048

typedef __attribute__((ext_vector_type(8))) short bf16x8;
typedef __attribute__((ext_vector_type(4))) float f32x4;

__device__ __forceinline__ unsigned pk2(float a, float b) {
    __hip_bfloat162 h = __float22bfloat162_rn(make_float2(a, b));
    union { __hip_bfloat162 h; unsigned u; } x;
    x.h = h;
    return x.u;  // low 16 = a, high 16 = b
}
__device__ __forceinline__ unsigned oh2(int a, int b, int c) {
    return (a == c ? 0x3F80u : 0u) | (b == c ? 0x3F800000u : 0u);  // bf16 {1.0,1.0}
}

// Pass 1: segment-sum via one-hot MFMA (layout verified in R3).
// Software-pipelined: per-wave double LDS buffer; next chunk's global loads
// issue before current chunk's MFMAs, pack+ds_write lands after them.
// Flush: PLAIN stores to a private slot per block. No atomics anywhere.
__global__ void __launch_bounds__(256) k_sums(const float4* __restrict__ feat,
                                              const int* __restrict__ lab,
                                              float* __restrict__ part) {
    __shared__ __align__(16) float smem[4 * 1088];  // 17408 B; wave w dbuf at bytes [w*4096, w*4096+4096)
    const int tid = threadIdx.x;
    const int l = tid & 63, w = tid >> 6, g = l >> 4, mcol = l & 15;
    const unsigned lds0 = (unsigned)(uintptr_t)(&smem[0]);

    f32x4 accS[4], accC[4];
#pragma unroll
    for (int i = 0; i < 4; ++i) {
        accS[i] = (f32x4){0.f, 0.f, 0.f, 0.f};
        accC[i] = (f32x4){0.f, 0.f, 0.f, 0.f};
    }
    bf16x8 ones;
#pragma unroll
    for (int i = 0; i < 8; ++i) ones[i] = (short)0x3F80;

    const int wstride = gridDim.x * 4;
    int wc = blockIdx.x * 4 + w;
    int cur = 0;
    int4 La0, Lb0, La1, Lb1;

    // prologue: load + stage chunk wc into buffer 0
    {
        const int P = wc * 64;
        float4 f0 = feat[P * 4 + l];
        float4 f1 = feat[P * 4 + 64 + l];
        float4 f2 = feat[P * 4 + 128 + l];
        float4 f3 = feat[P * 4 + 192 + l];
        La0 = *(const int4*)(lab + P + 4 * g);
        Lb0 = *(const int4*)(lab + P + 16 + 4 * g);
        La1 = *(const int4*)(lab + P + 32 + 4 * g);
        Lb1 = *(const int4*)(lab + P + 48 + 4 * g);
        uint2* tw = (uint2*)((char*)smem + w * 4096);
        tw[l]       = make_uint2(pk2(f0.x, f0.y), pk2(f0.z, f0.w));
        tw[64 + l]  = make_uint2(pk2(f1.x, f1.y), pk2(f1.z, f1.w));
        tw[128 + l] = make_uint2(pk2(f2.x, f2.y), pk2(f2.z, f2.w));
        tw[192 + l] = make_uint2(pk2(f3.x, f3.y), pk2(f3.z, f3.w));
    }

    while (wc * 64 < NPTS) {
        const int nwc = wc + wstride;
        const bool more = (nwc * 64 < NPTS);
        float4 g0, g1, g2, g3;
        int4 Ma0, Mb0, Ma1, Mb1;
        if (more) {  // issue next chunk's loads NOW; consumed after the MFMAs
            const int P = nwc * 64;
            g0 = feat[P * 4 + l];
            g1 = feat[P * 4 + 64 + l];
            g2 = feat[P * 4 + 128 + l];
            g3 = feat[P * 4 + 192 + l];
            Ma0 = *(const int4*)(lab + P + 4 * g);
            Mb0 = *(const int4*)(lab + P + 16 + 4 * g);
            Ma1 = *(const int4*)(lab + P + 32 + 4 * g);
            Mb1 = *(const int4*)(lab + P + 48 + 4 * g);
        }

        // tr-read current buffer (writes to it drained first)
        const unsigned trb = lds0 + (unsigned)(w * 4096 + cur * 2048 + l * 8);
        asm volatile("s_waitcnt lgkmcnt(0)" ::: "memory");
        unsigned long long t00, t01, t10, t11;
        asm volatile("ds_read_b64_tr_b16 %0, %1 offset:0"    : "=v"(t00) : "v"(trb));
        asm volatile("ds_read_b64_tr_b16 %0, %1 offset:512"  : "=v"(t01) : "v"(trb));
        asm volatile("ds_read_b64_tr_b16 %0, %1 offset:1024" : "=v"(t10) : "v"(trb));
        asm volatile("ds_read_b64_tr_b16 %0, %1 offset:1536" : "=v"(t11) : "v"(trb));
        asm volatile("s_waitcnt lgkmcnt(0)" ::: "memory");
        __builtin_amdgcn_sched_barrier(0);

        union { unsigned u[4]; bf16x8 h; } B0, B1;
        B0.u[0] = (unsigned)t00; B0.u[1] = (unsigned)(t00 >> 32);
        B0.u[2] = (unsigned)t01; B0.u[3] = (unsigned)(t01 >> 32);
        B1.u[0] = (unsigned)t10; B1.u[1] = (unsigned)(t10 >> 32);
        B1.u[2] = (unsigned)t11; B1.u[3] = (unsigned)(t11 >> 32);

#pragma unroll
        for (int gp = 0; gp < 4; ++gp) {
            const int c = mcol + (gp << 4);
            union { unsigned u[4]; bf16x8 h; } A0, A1;
            A0.u[0] = oh2(La0.x, La0.y, c); A0.u[1] = oh2(La0.z, La0.w, c);
            A0.u[2] = oh2(Lb0.x, Lb0.y, c); A0.u[3] = oh2(Lb0.z, Lb0.w, c);
            A1.u[0] = oh2(La1.x, La1.y, c); A1.u[1] = oh2(La1.z, La1.w, c);
            A1.u[2] = oh2(Lb1.x, Lb1.y, c); A1.u[3] = oh2(Lb1.z, Lb1.w, c);
            accS[gp] = __builtin_amdgcn_mfma_f32_16x16x32_bf16(A0.h, B0.h, accS[gp], 0, 0, 0);
            accC[gp] = __builtin_amdgcn_mfma_f32_16x16x32_bf16(A0.h, ones, accC[gp], 0, 0, 0);
            accS[gp] = __builtin_amdgcn_mfma_f32_16x16x32_bf16(A1.h, B1.h, accS[gp], 0, 0, 0);
            accC[gp] = __builtin_amdgcn_mfma_f32_16x16x32_bf16(A1.h, ones, accC[gp], 0, 0, 0);
        }

        // stage next chunk into the other buffer (overlaps with in-flight loads)
        if (more) {
            uint2* tw = (uint2*)((char*)smem + w * 4096 + (cur ^ 1) * 2048);
            tw[l]       = make_uint2(pk2(g0.x, g0.y), pk2(g0.z, g0.w));
            tw[64 + l]  = make_uint2(pk2(g1.x, g1.y), pk2(g1.z, g1.w));
            tw[128 + l] = make_uint2(pk2(g2.x, g2.y), pk2(g2.z, g2.w));
            tw[192 + l] = make_uint2(pk2(g3.x, g3.y), pk2(g3.z, g3.w));
            La0 = Ma0; Lb0 = Mb0; La1 = Ma1; Lb1 = Mb1;
        }
        wc = nwc;
        cur ^= 1;
    }

    // flush: D layout col=lane&15, row=(lane>>4)*4+reg (m89-verified)
    __syncthreads();
    float* fl = smem + w * 1088;
#pragma unroll
    for (int gp = 0; gp < 4; ++gp) {
#pragma unroll
        for (int r = 0; r < 4; ++r) {
            int c = (gp << 4) + ((l >> 4) << 2) + r;
            fl[c * 16 + mcol] = accS[gp][r];
            if (mcol == 0) fl[1024 + c] = accC[gp][r];
        }
    }
    __syncthreads();
    float* dst = part + (size_t)blockIdx.x * 1088;
    for (int i = tid; i < 1088; i += 256)
        dst[i] = smem[i] + smem[1088 + i] + smem[2176 + i] + smem[3264 + i];
}

// Tree-reduce part[NPART][1088] -> fs[1088] (sums 0..1023, counts 1024..1087)
__global__ void __launch_bounds__(256) k_reduce(const float* __restrict__ part,
                                                float* __restrict__ fs) {
    __shared__ float red[16][17];
    const int t = threadIdx.x, jl = t & 15, seg = t >> 4;
    const int j = blockIdx.x * 16 + jl;
    float a = 0.f;
    for (int p = seg; p < NPART; p += 16) a += part[p * 1088 + j];
    red[seg][jl] = a;
    __syncthreads();
    if (t < 16) {
        float s = 0.f;
#pragma unroll
        for (int k = 0; k < 16; ++k) s += red[k][t];
        fs[blockIdx.x * 16 + t] = s;
    }
}

// means, inv-counts, inter-pair hinge, reg norm. One block.
__global__ void __launch_bounds__(256) k_means_inter(const float* __restrict__ fs,
                                                     float* __restrict__ means,
                                                     float* __restrict__ icnt,
                                                     float* __restrict__ scal) {
    __shared__ float s_means[NCL * 17];
    __shared__ float red[8];
    int tid = threadIdx.x;
    for (int i = tid; i < NCL * 16; i += 256) {
        float m = fs[i] / fs[1024 + (i >> 4)];
        means[i] = m;
        s_means[(i >> 4) * 17 + (i & 15)] = m;
    }
    if (tid < NCL) icnt[tid] = 1.0f / fs[1024 + tid];
    __syncthreads();

    float inter = 0.f;
    for (int pr = tid; pr < NCL * NCL; pr += 256) {
        int i = pr >> 6, j = pr & 63;
        if (i != j) {
            float ss = 0.f;
#pragma unroll
            for (int k = 0; k < 16; ++k) {
                float dv = s_means[i * 17 + k] - s_means[j * 17 + k] + EPSF;
                ss += dv * dv;
            }
            float h = fmaxf(3.0f - sqrtf(ss), 0.f);  // 2*INTER_MARGIN
            inter += h * h;
        }
    }
    float reg = 0.f;
    if (tid < NCL) {
        float ss = 0.f;
#pragma unroll
        for (int k = 0; k < 16; ++k) {
            float m = s_means[tid * 17 + k] + EPSF;
            ss += m * m;
        }
        reg = sqrtf(ss);
    }
#pragma unroll
    for (int m = 1; m < 64; m <<= 1) {
        inter += __shfl_xor(inter, m);
        reg += __shfl_xor(reg, m);
    }
    int wave = tid >> 6;
    if ((tid & 63) == 0) { red[wave] = inter; red[4 + wave] = reg; }
    __syncthreads();
    if (tid == 0) {
        scal[0] = (red[0] + red[1] + red[2] + red[3]) / (float)(NCL * (NCL - 1));
        scal[1] = (red[4] + red[5] + red[6] + red[7]) / (float)NCL;
    }
}

// Pass 2: acc += h^2 * inv_cnt[label] in registers. Plain per-block partial store.
__global__ void __launch_bounds__(256) k_intra(const float4* __restrict__ feat,
                                               const int* __restrict__ lab,
                                               const float* __restrict__ means,
                                               const float* __restrict__ icnt,
                                               float* __restrict__ pintra) {
    __shared__ float s_m[NCL * 17];
    __shared__ float r4[4];
    const int tid = threadIdx.x;
    for (int i = tid; i < NCL * 16; i += 256)
        s_m[(i >> 4) * 17 + (i & 15)] = means[i];
    for (int i = tid; i < NCL; i += 256) s_m[i * 17 + 16] = icnt[i];
    __syncthreads();

    float acc = 0.f;
    const int total = NPTS * 4;
    const int stride = gridDim.x * 256;
    for (int idx = blockIdx.x * 256 + tid; idx < total; idx += stride) {
        int p = idx >> 2, q = idx & 3;
        int lb = lab[p];
        float4 v = feat[idx];
        const float* m = &s_m[lb * 17 + q * 4];
        float d0 = v.x - m[0] + EPSF;
        float d1 = v.y - m[1] + EPSF;
        float d2 = v.z - m[2] + EPSF;
        float d3 = v.w - m[3] + EPSF;
        float ss = d0 * d0 + d1 * d1 + d2 * d2 + d3 * d3;
        ss += __shfl_xor(ss, 1);
        ss += __shfl_xor(ss, 2);
        if (q == 0) {
            float h = fmaxf(sqrtf(ss) - 0.5f, 0.f);
            acc += h * h * s_m[lb * 17 + 16];
        }
    }
#pragma unroll
    for (int mm = 1; mm < 64; mm <<= 1) acc += __shfl_xor(acc, mm);
    if ((tid & 63) == 0) r4[tid >> 6] = acc;
    __syncthreads();
    if (tid == 0) pintra[blockIdx.x] = r4[0] + r4[1] + r4[2] + r4[3];
}

__global__ void k_final(const float* __restrict__ pintra, const float* __restrict__ scal,
                        float* __restrict__ out) {
    int t = threadIdx.x;  // 256
    float v = 0.f;
#pragma unroll
    for (int i = 0; i < NB_INTRA / 256; ++i) v += pintra[t + i * 256];
#pragma unroll
    for (int mm = 1; mm < 64; mm <<= 1) v += __shfl_xor(v, mm);
    __shared__ float r4[4];
    if ((t & 63) == 0) r4[t >> 6] = v;
    __syncthreads();
    if (t == 0) out[0] = (r4[0] + r4[1] + r4[2] + r4[3]) / (float)NCL + scal[0] + 0.001f * scal[1];
}

extern "C" void kernel_launch(void* const* d_in, const int* in_sizes, int n_in,
                              void* d_out, int out_size, void* d_ws, size_t ws_size,
                              hipStream_t stream) {
    const float4* feat = (const float4*)d_in[0];
    const int* lab = (const int*)d_in[1];
    float* ws = (float*)d_ws;
    float* out = (float*)d_out;

    // ws layout (floats): part[NPART][1088] | fs[1088] | means[1024] | icnt[64] | scal[2] | pintra[NB_INTRA]
    float* part = ws;
    float* fs = part + (size_t)NPART * 1088;
    float* means = fs + 1088;
    float* icnt = means + 1024;
    float* scal = icnt + 64;
    float* pintra = scal + 2;

    // Every ws word read is written first this call — no memset, no atomics.
    k_sums<<<NB_SUMS, 256, 0, stream>>>(feat, lab, part);
    k_reduce<<<68, 256, 0, stream>>>(part, fs);
    k_means_inter<<<1, 256, 0, stream>>>(fs, means, icnt, scal);
    k_intra<<<NB_INTRA, 256, 0, stream>>>(feat, lab, means, icnt, pintra);
    k_final<<<1, 256, 0, stream>>>(pintra, scal, out);
}

// Round 8
// 79.723 us; speedup vs baseline: 5.3255x; 1.0311x over previous
//
#include <hip/hip_runtime.h>
#include <hip/hip_bf16.h>
#include <math.h>

#define NPTS 2000000
#define NCL 64
#define EPSF 1e-8f
#define NB_SUMS 1024
#define NPART 1024
#define NB_INTRA 2048

typedef __attribute__((ext_vector_type(8))) short bf16x8;
typedef __attribute__((ext_vector_type(4))) float f32x4;

__device__ __forceinline__ unsigned pk2(float a, float b) {
    __hip_bfloat162 h = __float22bfloat162_rn(make_float2(a, b));
    union { __hip_bfloat162 h; unsigned u; } x;
    x.h = h;
    return x.u;  // low 16 = a, high 16 = b
}
__device__ __forceinline__ unsigned oh2(int a, int b, int c) {
    return (a == c ? 0x3F80u : 0u) | (b == c ? 0x3F800000u : 0u);  // bf16 {1.0,1.0}
}

// Pass 1: segment-sum via one-hot MFMA, B built DIRECTLY from global (no LDS
// in the main loop, no barriers, no waits). Identity k<->point mapping:
// lane l holds B[k=8*(l>>4)+j][dim=l&15] = feat[P + 8*(l>>4) + j][l&15],
// A[row=c][k] = (lab[P+k]==c), both built in registers. Counts via ones-B.
// Flush: plain stores to a private per-block slot. No atomics anywhere.
__global__ void __launch_bounds__(256) k_sums(const float* __restrict__ feat,
                                              const int* __restrict__ lab,
                                              float* __restrict__ part) {
    __shared__ __align__(16) float smem[4 * 1088];  // epilogue only
    const int tid = threadIdx.x;
    const int l = tid & 63, w = tid >> 6, g = l >> 4, mcol = l & 15;

    f32x4 accS[4], accC[4];
#pragma unroll
    for (int i = 0; i < 4; ++i) {
        accS[i] = (f32x4){0.f, 0.f, 0.f, 0.f};
        accC[i] = (f32x4){0.f, 0.f, 0.f, 0.f};
    }
    bf16x8 ones;
#pragma unroll
    for (int i = 0; i < 8; ++i) ones[i] = (short)0x3F80;

    const int wstride = gridDim.x * 4;
    for (int wc = blockIdx.x * 4 + w; wc * 64 < NPTS; wc += wstride) {
        const int P = wc * 64;
        // B-loads: stride-64B dwords; each 16-lane group covers one 64B line.
        const float* fb = feat + (P + 8 * g) * 16 + mcol;
        float x0 = fb[0],   x1 = fb[16],  x2 = fb[32],  x3 = fb[48];
        float x4 = fb[64],  x5 = fb[80],  x6 = fb[96],  x7 = fb[112];
        float y0 = fb[512], y1 = fb[528], y2 = fb[544], y3 = fb[560];
        float y4 = fb[576], y5 = fb[592], y6 = fb[608], y7 = fb[624];
        // labels for k-slices this lane-group covers (points P+8g.. / P+32+8g..)
        int4 La = *(const int4*)(lab + P + 8 * g);
        int4 Lb = *(const int4*)(lab + P + 8 * g + 4);
        int4 Ma = *(const int4*)(lab + P + 32 + 8 * g);
        int4 Mb = *(const int4*)(lab + P + 32 + 8 * g + 4);

        union { unsigned u[4]; bf16x8 h; } B0, B1;
        B0.u[0] = pk2(x0, x1); B0.u[1] = pk2(x2, x3);
        B0.u[2] = pk2(x4, x5); B0.u[3] = pk2(x6, x7);
        B1.u[0] = pk2(y0, y1); B1.u[1] = pk2(y2, y3);
        B1.u[2] = pk2(y4, y5); B1.u[3] = pk2(y6, y7);

#pragma unroll
        for (int gp = 0; gp < 4; ++gp) {
            const int c = mcol + (gp << 4);
            union { unsigned u[4]; bf16x8 h; } A0, A1;
            A0.u[0] = oh2(La.x, La.y, c); A0.u[1] = oh2(La.z, La.w, c);
            A0.u[2] = oh2(Lb.x, Lb.y, c); A0.u[3] = oh2(Lb.z, Lb.w, c);
            A1.u[0] = oh2(Ma.x, Ma.y, c); A1.u[1] = oh2(Ma.z, Ma.w, c);
            A1.u[2] = oh2(Mb.x, Mb.y, c); A1.u[3] = oh2(Mb.z, Mb.w, c);
            accS[gp] = __builtin_amdgcn_mfma_f32_16x16x32_bf16(A0.h, B0.h, accS[gp], 0, 0, 0);
            accC[gp] = __builtin_amdgcn_mfma_f32_16x16x32_bf16(A0.h, ones, accC[gp], 0, 0, 0);
            accS[gp] = __builtin_amdgcn_mfma_f32_16x16x32_bf16(A1.h, B1.h, accS[gp], 0, 0, 0);
            accC[gp] = __builtin_amdgcn_mfma_f32_16x16x32_bf16(A1.h, ones, accC[gp], 0, 0, 0);
        }
    }

    // flush: D layout col=lane&15, row=(lane>>4)*4+reg (m89-verified)
    __syncthreads();
    float* fl = smem + w * 1088;
#pragma unroll
    for (int gp = 0; gp < 4; ++gp) {
#pragma unroll
        for (int r = 0; r < 4; ++r) {
            int c = (gp << 4) + ((l >> 4) << 2) + r;
            fl[c * 16 + mcol] = accS[gp][r];
            if (mcol == 0) fl[1024 + c] = accC[gp][r];
        }
    }
    __syncthreads();
    float* dst = part + (size_t)blockIdx.x * 1088;
    for (int i = tid; i < 1088; i += 256)
        dst[i] = smem[i] + smem[1088 + i] + smem[2176 + i] + smem[3264 + i];
}

// Reduce part[NPART][1088] -> means[64][16], icnt[64]. Block b owns cluster b:
// sums its 16 sum-columns and its count-column across all partials.
__global__ void __launch_bounds__(256) k_reduce_means(const float* __restrict__ part,
                                                      float* __restrict__ means,
                                                      float* __restrict__ icnt) {
    __shared__ float red[16][17];
    __shared__ float cred[16];
    const int t = threadIdx.x, jl = t & 15, seg = t >> 4;
    const int b = blockIdx.x;
    float a = 0.f, c = 0.f;
    for (int p = seg; p < NPART; p += 16) {
        a += part[p * 1088 + b * 16 + jl];
        if (jl == 0) c += part[p * 1088 + 1024 + b];
    }
    red[seg][jl] = a;
    if (jl == 0) cred[seg] = c;
    __syncthreads();
    if (t < 16) {
        float s = 0.f, cnt = 0.f;
#pragma unroll
        for (int k = 0; k < 16; ++k) { s += red[k][t]; cnt += cred[k]; }
        means[b * 16 + t] = s / cnt;
        if (t == 0) icnt[b] = 1.0f / cnt;
    }
}

// Pass 2: acc += h^2 * inv_cnt[label] in registers. Plain per-block partial store.
__global__ void __launch_bounds__(256) k_intra(const float4* __restrict__ feat,
                                               const int* __restrict__ lab,
                                               const float* __restrict__ means,
                                               const float* __restrict__ icnt,
                                               float* __restrict__ pintra) {
    __shared__ float s_m[NCL * 17];
    __shared__ float r4[4];
    const int tid = threadIdx.x;
    for (int i = tid; i < NCL * 16; i += 256)
        s_m[(i >> 4) * 17 + (i & 15)] = means[i];
    for (int i = tid; i < NCL; i += 256) s_m[i * 17 + 16] = icnt[i];
    __syncthreads();

    float acc = 0.f;
    const int total = NPTS * 4;
    const int stride = gridDim.x * 256;
    for (int idx = blockIdx.x * 256 + tid; idx < total; idx += stride) {
        int p = idx >> 2, q = idx & 3;
        int lb = lab[p];
        float4 v = feat[idx];
        const float* m = &s_m[lb * 17 + q * 4];
        float d0 = v.x - m[0] + EPSF;
        float d1 = v.y - m[1] + EPSF;
        float d2 = v.z - m[2] + EPSF;
        float d3 = v.w - m[3] + EPSF;
        float ss = d0 * d0 + d1 * d1 + d2 * d2 + d3 * d3;
        ss += __shfl_xor(ss, 1);
        ss += __shfl_xor(ss, 2);
        if (q == 0) {
            float h = fmaxf(sqrtf(ss) - 0.5f, 0.f);
            acc += h * h * s_m[lb * 17 + 16];
        }
    }
#pragma unroll
    for (int mm = 1; mm < 64; mm <<= 1) acc += __shfl_xor(acc, mm);
    if ((tid & 63) == 0) r4[tid >> 6] = acc;
    __syncthreads();
    if (tid == 0) pintra[blockIdx.x] = r4[0] + r4[1] + r4[2] + r4[3];
}

// Final: inter-pair hinge + reg norm from means, sum pintra, combine. One block.
__global__ void __launch_bounds__(256) k_final(const float* __restrict__ means,
                                               const float* __restrict__ pintra,
                                               float* __restrict__ out) {
    __shared__ float s_means[NCL * 17];
    __shared__ float red[12];
    const int tid = threadIdx.x;
    for (int i = tid; i < NCL * 16; i += 256)
        s_means[(i >> 4) * 17 + (i & 15)] = means[i];
    __syncthreads();

    float inter = 0.f;
    for (int pr = tid; pr < NCL * NCL; pr += 256) {
        int i = pr >> 6, j = pr & 63;
        if (i != j) {
            float ss = 0.f;
#pragma unroll
            for (int k = 0; k < 16; ++k) {
                float dv = s_means[i * 17 + k] - s_means[j * 17 + k] + EPSF;
                ss += dv * dv;
            }
            float h = fmaxf(3.0f - sqrtf(ss), 0.f);  // 2*INTER_MARGIN
            inter += h * h;
        }
    }
    float reg = 0.f;
    if (tid < NCL) {
        float ss = 0.f;
#pragma unroll
        for (int k = 0; k < 16; ++k) {
            float m = s_means[tid * 17 + k] + EPSF;
            ss += m * m;
        }
        reg = sqrtf(ss);
    }
    float pin = 0.f;
#pragma unroll
    for (int i = 0; i < NB_INTRA / 256; ++i) pin += pintra[tid + i * 256];

#pragma unroll
    for (int m = 1; m < 64; m <<= 1) {
        inter += __shfl_xor(inter, m);
        reg += __shfl_xor(reg, m);
        pin += __shfl_xor(pin, m);
    }
    const int wv = tid >> 6;
    if ((tid & 63) == 0) { red[wv] = inter; red[4 + wv] = reg; red[8 + wv] = pin; }
    __syncthreads();
    if (tid == 0) {
        float it = (red[0] + red[1] + red[2] + red[3]) / (float)(NCL * (NCL - 1));
        float rg = (red[4] + red[5] + red[6] + red[7]) / (float)NCL;
        float ia = (red[8] + red[9] + red[10] + red[11]) / (float)NCL;
        out[0] = ia + it + 0.001f * rg;
    }
}

extern "C" void kernel_launch(void* const* d_in, const int* in_sizes, int n_in,
                              void* d_out, int out_size, void* d_ws, size_t ws_size,
                              hipStream_t stream) {
    const float* feat = (const float*)d_in[0];
    const int* lab = (const int*)d_in[1];
    float* ws = (float*)d_ws;
    float* out = (float*)d_out;

    // ws layout (floats): part[NPART][1088] | means[1024] | icnt[64] | pintra[NB_INTRA]
    float* part = ws;
    float* means = part + (size_t)NPART * 1088;
    float* icnt = means + 1024;
    float* pintra = icnt + 64;

    // Every ws word read is written first this call — no memset, no atomics.
    k_sums<<<NB_SUMS, 256, 0, stream>>>(feat, lab, part);
    k_reduce_means<<<NCL, 256, 0, stream>>>(part, means, icnt);
    k_intra<<<NB_INTRA, 256, 0, stream>>>((const float4*)feat, lab, means, icnt, pintra);
    k_final<<<1, 256, 0, stream>>>(means, pintra, out);
}